// Round 9
// baseline (126.568 us; speedup 1.0000x reference)
//
#include <hip/hip_runtime.h>

#define NPTS 8192      // H*W
#define BCLS 4         // C
#define NP   6         // B*(C-1) pairs
#define R2   9.0f
#define RAD  3.0f
#define GRD  128       // fine grid — cell = max(6, span/127) ~= 2*RAD
#define NCELL (GRD*GRD)
#define PCAP 2048      // pending-list capacity (overflow -> sweep fallback)
#define LDSK 2048      // LDS kept-center accumulator cap (multi-pass if exceeded)
#define CAP  4096      // per-pair compact-point capacity (M ~ 2048 +- 40)
#define KBLK 64        // front kernel blocks
#define KTHR 256       // front kernel threads (KBLK*KTHR == B*NPTS)

#define ST_U 0u
#define ST_A 1u
#define ST_D 2u

// ---------------------------------------------------------------------------
// R22 = R21 (101.7 total, k_nms 48.1) + round-phase reduction in the pending
// loop ONLY. R20 post-mortem: 4.5x scan-volume cut bought just 4.4us => the
// ~20us residual is the BARRIER-PHASE structure of the fixed point (~40
// rounds x 2 barriers x skewed max-wave wait), not scan work (R15/R16 bound
// rounds>=2 scans at <=3us). Edits:
//  (a) rotating 3-counter rounds (R14-proven correct): read c[r%3], append
//      c[(r+1)%3], reset c[(r+2)%3] => inner reset barrier gone (1/round).
//  (b) K=4 intra-round passes for PENDING rounds only (round-0 untouched —
//      R14's +3us came from double-scanning round-0): an undecided item
//      rescans up to 3 more times after publishing; decisions are program-
//      order visible within the wave and chains are grid-local => collapses
//      ~4 dependency layers per barrier-round; rounds ~40 -> ~10-14.
// Monotone U->{A,D} word-granular framework unchanged; progress argument
// unchanged (min-index pending resolves in pass 1 of its round).
// ---------------------------------------------------------------------------

__global__ __launch_bounds__(KTHR) void k_front(
    const float* __restrict__ seg, const float* __restrict__ lidar,
    float* __restrict__ xs, float* __restrict__ ys,
    unsigned int* __restrict__ ns, unsigned int* __restrict__ counts,
    float* __restrict__ out)
{
    const int tid = threadIdx.x, lane = tid & 63;
    const int idx = blockIdx.x * KTHR + tid;       // [0, B*NPTS)
    const int b = idx >> 13, n = idx & 8191;

    __shared__ float ex[KTHR], ey[KTHR];
    __shared__ unsigned short en[KTHR];
    __shared__ unsigned int cnt6[6], off6[6], pos6[6];

    if (tid < 6) cnt6[tid] = 0;
    __syncthreads();

    // per-pixel argmax (strict >: first index wins ties)
    const float* segb = seg + (size_t)b * BCLS * NPTS + n;
    float bv = segb[0];
    int bc = 0;
    #pragma unroll
    for (int c = 1; c < BCLS; ++c) {
        float v = segb[(size_t)c * NPTS];
        if (v > bv) { bv = v; bc = c; }
    }
    const float x = lidar[(size_t)b * 2 * NPTS + n];
    const float y = lidar[(size_t)b * 2 * NPTS + NPTS + n];
    const int p = (bc > 0) ? (b * 3 + bc - 1) : -1;

    // phase A: wave-aggregated per-pair counts
    #pragma unroll
    for (int q = 0; q < 6; ++q) {
        unsigned long long bal = __ballot(p == q);
        if (lane == 0 && bal) atomicAdd(&cnt6[q], (unsigned int)__popcll(bal));
    }
    __syncthreads();
    if (tid == 0) {
        unsigned int a = 0;
        #pragma unroll
        for (int q = 0; q < 6; ++q) { off6[q] = a; pos6[q] = a; a += cnt6[q]; }
    }
    __syncthreads();
    // phase B: wave-aggregated placement into pair-grouped staging
    #pragma unroll
    for (int q = 0; q < 6; ++q) {
        unsigned long long bal = __ballot(p == q);
        if (bal) {
            int ldr = __builtin_ctzll(bal);
            unsigned int wb = 0;
            if (lane == ldr) wb = atomicAdd(&pos6[q], (unsigned int)__popcll(bal));
            wb = __shfl(wb, ldr, 64);
            if (p == q) {
                unsigned int s = wb + (unsigned int)__popcll(bal & ((1ull << lane) - 1ull));
                ex[s] = x; ey[s] = y; en[s] = (unsigned short)n;
            }
        }
    }
    __syncthreads();
    // flush grouped staging to this block's slab chunk + counts row
    {
        const unsigned int total = off6[5] + cnt6[5];
        const int gbase = blockIdx.x * KTHR;
        for (int k = tid; k < (int)total; k += KTHR) {
            xs[gbase + k] = ex[k];
            ys[gbase + k] = ey[k];
            ns[gbase + k] = (unsigned int)en[k];
        }
        if (tid < 6) counts[blockIdx.x * 6 + tid] = cnt6[tid];
    }
    // zero out+ok: (2*NP*NPTS + NP*NPTS) floats = 147456 = 36864 float4
    {
        float4* o4 = (float4*)out;
        for (int k = idx; k < 36864; k += KBLK * KTHR)
            o4[k] = make_float4(0.f, 0.f, 0.f, 0.f);
    }
}

__global__ __launch_bounds__(1024) void k_nms(
    const float* __restrict__ xs, const float* __restrict__ ys,
    const unsigned int* __restrict__ ns, const unsigned int* __restrict__ counts,
    float* __restrict__ out)
{
    const int p = blockIdx.x;
    const int tid = threadIdx.x, lane = tid & 63, wv = tid >> 6;
    const int base = p * NPTS;

    __shared__ float2 sps[CAP];                 // 32 KB: grid-space coords
    __shared__ unsigned int cmb[CAP];           // 16 KB: pixel<<2 | status
    __shared__ unsigned int cellpack[NCELL];    // 64 KB: start<<16 | cnt
    __shared__ unsigned short plist[2][PCAP];   //  8 KB
    __shared__ float ksx[LDSK], ksy[LDSK], kcn[LDSK];  // 24 KB
    __shared__ int pcnt3[3];                    // rotating round counters
    __shared__ unsigned long long ballots[64];  // kept-rank words (CAP/64)
    __shared__ unsigned int base64[64];
    __shared__ unsigned int wtot[16];
    __shared__ float redbuf[4][16];
    __shared__ unsigned int csrc[KBLK], cdst[KBLK];
    __shared__ float sbminx, sbminy, scell;
    __shared__ int sM, sK;

    float* ok = out + (size_t)2 * NP * NPTS + base;

    // ---- P0: zero LDS state (out/ok zeroed by k_front) ----
    for (int k = tid; k < CAP; k += 1024) cmb[k] = ST_U;
    for (int k = tid; k < NCELL; k += 1024) cellpack[k] = 0u;
    for (int k = tid; k < LDSK; k += 1024) { ksx[k] = 0.f; ksy[k] = 0.f; kcn[k] = 0.f; }
    if (tid == 0) { pcnt3[0] = 0; pcnt3[1] = 0; pcnt3[2] = 0; }

    // ---- chunk table: lane k of wave 0 owns source block k ----
    if (wv == 0) {
        unsigned int c6[6];
        #pragma unroll
        for (int q = 0; q < 6; ++q) c6[q] = counts[lane * 6 + q];
        unsigned int within = 0;
        for (int q = 0; q < p; ++q) within += c6[q];
        unsigned int len = c6[p];
        unsigned int v = len;
        for (int d = 1; d < 64; d <<= 1) {
            unsigned int u = __shfl_up(v, d, 64);
            if (lane >= d) v += u;
        }
        csrc[lane] = lane * KTHR + within;
        cdst[lane] = v - len;
        if (lane == 63) sM = (int)(v < CAP ? v : CAP);
    }
    __syncthreads();
    const int M = sM;

    // ---- gather compact entries into regs + bbox (M <= CAP = 4096) ----
    float xq[4], yq[4];
    unsigned int nq[4];
    int liq[4];
    {
        float mnx = 3e38f, mxx = -3e38f, mny = 3e38f, mxy = -3e38f;
        #pragma unroll
        for (int q = 0; q < 4; ++q) {
            int li = q * 1024 + tid;
            liq[q] = li;
            if (li < M) {
                int lo = 0, hi = KBLK - 1;          // last k with cdst[k] <= li
                #pragma unroll
                for (int s = 0; s < 6; ++s) {
                    int mid = (lo + hi + 1) >> 1;
                    if (cdst[mid] <= (unsigned int)li) lo = mid; else hi = mid - 1;
                }
                int si = csrc[lo] + (li - cdst[lo]);
                float x = xs[si], y = ys[si];
                xq[q] = x; yq[q] = y; nq[q] = ns[si];
                mnx = fminf(mnx, x); mxx = fmaxf(mxx, x);
                mny = fminf(mny, y); mxy = fmaxf(mxy, y);
            }
        }
        for (int d = 32; d; d >>= 1) {
            mnx = fminf(mnx, __shfl_xor(mnx, d, 64));
            mxx = fmaxf(mxx, __shfl_xor(mxx, d, 64));
            mny = fminf(mny, __shfl_xor(mny, d, 64));
            mxy = fmaxf(mxy, __shfl_xor(mxy, d, 64));
        }
        if (lane == 0) { redbuf[0][wv] = mnx; redbuf[1][wv] = mxx;
                         redbuf[2][wv] = mny; redbuf[3][wv] = mxy; }
    }
    __syncthreads();
    if (tid == 0) {
        float a = redbuf[0][0], b2 = redbuf[1][0], c = redbuf[2][0], d = redbuf[3][0];
        for (int q = 1; q < 16; ++q) {
            a = fminf(a, redbuf[0][q]); b2 = fmaxf(b2, redbuf[1][q]);
            c = fminf(c, redbuf[2][q]); d = fmaxf(d, redbuf[3][q]);
        }
        sbminx = a; sbminy = c;
        scell = fmaxf(2.0f * RAD, fmaxf(b2 - a, d - c) / 127.0f);  // cell >= 2*RAD
    }
    __syncthreads();
    const float bminx = sbminx, bminy = sbminy, inv = 1.0f / scell;

    // ---- grid count / scan / scatter (coords held in regs) ----
    int cellq[4];
    #pragma unroll
    for (int q = 0; q < 4; ++q) {
        if (liq[q] < M) {
            int ix = min(GRD - 1, max(0, (int)((xq[q] - bminx) * inv)));
            int iy = min(GRD - 1, max(0, (int)((yq[q] - bminy) * inv)));
            cellq[q] = iy * GRD + ix;
            atomicAdd(&cellpack[cellq[q]], 1u);
        } else cellq[q] = -1;
    }
    __syncthreads();
    {
        unsigned int c16[16], t16 = 0;          // thread owns 16 cells
        #pragma unroll
        for (int q = 0; q < 16; ++q) { c16[q] = cellpack[tid * 16 + q]; t16 += c16[q]; }
        unsigned int v = t16;
        for (int d = 1; d < 64; d <<= 1) {
            unsigned int u = __shfl_up(v, d, 64);
            if (lane >= d) v += u;
        }
        if (lane == 63) wtot[wv] = v;
        __syncthreads();
        if (tid == 0) {
            unsigned int acc = 0;
            for (int q = 0; q < 16; ++q) { unsigned int t = wtot[q]; wtot[q] = acc; acc += t; }
        }
        __syncthreads();
        unsigned int excl = wtot[wv] + v - t16;
        #pragma unroll
        for (int q = 0; q < 16; ++q) { cellpack[tid * 16 + q] = excl << 16; excl += c16[q]; }
    }
    __syncthreads();
    #pragma unroll
    for (int q = 0; q < 4; ++q) {
        if (cellq[q] >= 0) {
            unsigned int old = atomicAdd(&cellpack[cellq[q]], 1u);
            unsigned int pos = (old >> 16) + (old & 0xffffu);
            sps[pos] = make_float2(xq[q], yq[q]);
            cmb[pos] = (nq[q] << 2) | ST_U;
        }
    }   // cellpack now = start<<16 | cnt; sps/cmb grid-space
    __syncthreads();

    // flat window row scan over two contiguous streams (branchless)
    #define ROW_FLAGS(CY, CX0, CX1, NI, ME, DEAD, UNDEC)                          \
    {                                                                             \
        unsigned int wa = cellpack[(CY) * GRD + (CX0)];                           \
        unsigned int wb = cellpack[(CY) * GRD + (CX1)];                           \
        unsigned int f0 = wa >> 16, f1 = (wb >> 16) + (wb & 0xffffu);             \
        for (unsigned int f = f0; f < f1; ++f) {                                  \
            unsigned int wf = cmb[f];                                             \
            float2 q = sps[f];                                                    \
            float dx = __fsub_rn((ME).x, q.x), dy = __fsub_rn((ME).y, q.y);       \
            float d2 = __fadd_rn(__fmul_rn(dx, dx), __fmul_rn(dy, dy));           \
            bool in = (d2 < R2) & ((int)(wf >> 2) < (NI));                        \
            DEAD  |= in & ((wf & 3u) == ST_A);                                    \
            UNDEC |= in & ((wf & 3u) == ST_U);                                    \
        }                                                                         \
    }
    #define SCAN_FLAGS(NI, ME, DEAD, UNDEC)                                       \
    {                                                                             \
        int cx0 = max(0, (int)(((ME).x - RAD - bminx) * inv));                    \
        int cx1 = min(GRD - 1, (int)(((ME).x + RAD - bminx) * inv));              \
        int cy0 = max(0, (int)(((ME).y - RAD - bminy) * inv));                    \
        int cy1 = min(GRD - 1, (int)(((ME).y + RAD - bminy) * inv));              \
        DEAD = false; UNDEC = false;                                              \
        ROW_FLAGS(cy0, cx0, cx1, NI, ME, DEAD, UNDEC);                            \
        if (cy1 > cy0) ROW_FLAGS(cy1, cx0, cx1, NI, ME, DEAD, UNDEC);             \
    }

    // ---- P4 round 0: full sweep (grid order), wave-ordered pending append ----
    for (int e = tid; e < M; e += 1024) {
        unsigned int w = cmb[e];
        int ni = (int)(w >> 2);
        float2 me = sps[e];
        bool dead, undec;
        SCAN_FLAGS(ni, me, dead, undec);
        if (dead) cmb[e] = (w & ~3u) | ST_D;
        else if (!undec) cmb[e] = (w & ~3u) | ST_A;
        bool pendf = !dead && undec;
        unsigned long long act = __ballot(true);
        unsigned long long bal = __ballot(pendf);
        int leader = __builtin_ctzll(act);
        int cnt = __popcll(bal);
        int wbase = 0;
        if (lane == leader && cnt) wbase = atomicAdd(&pcnt3[0], cnt);
        wbase = __shfl(wbase, leader, 64);
        if (pendf) {
            int pos = wbase + __popcll(bal & ((1ull << lane) - 1ull));
            if (pos < PCAP) plist[0][pos] = (unsigned short)e;
        }
    }

    // ---- P4 rounds: ONE barrier/round (3-counter rotation) + K=4 passes ----
    int cur = 0;
    for (int round = 0; round < NPTS; ++round) {
        const int r3 = round % 3;
        __syncthreads();
        int pc = pcnt3[r3];
        if (pc == 0) break;
        if (pc > PCAP) {                        // overflow fallback: full sweeps
            for (;;) {
                bool any = false;
                __syncthreads();
                for (int e = tid; e < M; e += 1024) {
                    unsigned int w = cmb[e];
                    if ((w & 3u) != ST_U) continue;
                    int ni = (int)(w >> 2);
                    float2 me = sps[e];
                    bool dead, undec;
                    SCAN_FLAGS(ni, me, dead, undec);
                    if (dead) cmb[e] = (w & ~3u) | ST_D;
                    else if (!undec) cmb[e] = (w & ~3u) | ST_A;
                    else any = true;
                }
                if (__syncthreads_count(any) == 0) break;
            }
            break;
        }
        if (tid == 0) pcnt3[(r3 + 2) % 3] = 0;  // future counter: untouched this round
        for (int idx = tid; idx < pc; idx += 1024) {
            int e = plist[cur][idx];
            unsigned int w = cmb[e];
            int ni = (int)(w >> 2);
            float2 me = sps[e];
            bool pendf = false;
            #pragma unroll 1
            for (int ps = 0; ps < 4; ++ps) {    // K=4 layer-collapse passes
                bool dead, undec;
                SCAN_FLAGS(ni, me, dead, undec);
                if (dead) { cmb[e] = (w & ~3u) | ST_D; pendf = false; break; }
                if (!undec) { cmb[e] = (w & ~3u) | ST_A; pendf = false; break; }
                pendf = true;                   // publish-before-rescan: none to
            }                                   // publish (still U); loop rescans
            unsigned long long act = __ballot(true);
            unsigned long long bal = __ballot(pendf);
            int leader = __builtin_ctzll(act);
            int cnt = __popcll(bal);
            int wbase = 0;
            if (lane == leader && cnt) wbase = atomicAdd(&pcnt3[(r3 + 1) % 3], cnt);
            wbase = __shfl(wbase, leader, 64);
            if (pendf) {
                int pos = wbase + __popcll(bal & ((1ull << lane) - 1ull));
                if (pos < PCAP) plist[cur ^ 1][pos] = (unsigned short)e;
            }
        }
        cur ^= 1;
    }
    __syncthreads();

    // ---- kept-rank over grid space: ballot bitmask + wave-scanned prefix ----
    for (int k = 0; k < 4; ++k) {
        int e = (k << 10) + tid;
        unsigned long long bal = __ballot((cmb[e] & 3u) == ST_A);  // e>=M stays U
        if (lane == 0) ballots[(k << 4) + wv] = bal;
    }
    __syncthreads();
    if (wv == 0) {
        unsigned int s = (unsigned int)__popcll(ballots[lane]);
        unsigned int v = s;
        for (int d = 1; d < 64; d <<= 1) {
            unsigned int u = __shfl_up(v, d, 64);
            if (lane >= d) v += u;
        }
        base64[lane] = v - s;
        if (lane == 63) sK = (int)v;
    }
    __syncthreads();
    #define KRANK(E) ((int)base64[(E) >> 6] +                                     \
                      __popcll(ballots[(E) >> 6] & ((1ull << ((E) & 63)) - 1ull)))

    // ---- P5+P6: rank-windowed passes (1 pass when sK <= LDSK: the norm) ----
    #define ROW_ARGMIN(CY, CX0, CX1, ME, BD, BE, BN)                              \
    {                                                                             \
        unsigned int wa = cellpack[(CY) * GRD + (CX0)];                           \
        unsigned int wb = cellpack[(CY) * GRD + (CX1)];                           \
        unsigned int f0 = wa >> 16, f1 = (wb >> 16) + (wb & 0xffffu);             \
        for (unsigned int f = f0; f < f1; ++f) {                                  \
            unsigned int wf = cmb[f];                                             \
            float2 q = sps[f];                                                    \
            float dx = __fsub_rn((ME).x, q.x), dy = __fsub_rn((ME).y, q.y);       \
            float d2 = __fadd_rn(__fmul_rn(dx, dx), __fmul_rn(dy, dy));           \
            int nf = (int)(wf >> 2);                                              \
            bool better = ((wf & 3u) == ST_A) &                                   \
                          ((d2 < BD) | ((d2 == BD) & (nf < BN)));                 \
            BD = better ? d2 : BD;                                                \
            BE = better ? (int)f : BE;                                            \
            BN = better ? nf : BN;                                                \
        }                                                                         \
    }
    const int npass = (sK + LDSK - 1) / LDSK;
    for (int pass = 0; pass < npass; ++pass) {
        const int rb = pass * LDSK;
        if (pass) {
            __syncthreads();
            for (int k = tid; k < LDSK; k += 1024) { ksx[k] = 0.f; ksy[k] = 0.f; kcn[k] = 0.f; }
        }
        __syncthreads();
        for (int e = tid; e < M; e += 1024) {
            unsigned int w = cmb[e];
            float2 me = sps[e];
            int be;
            if ((w & 3u) == ST_A) {
                be = e;                          // self: unique d2 = 0
            } else {
                int cx0 = max(0, (int)((me.x - RAD - bminx) * inv));
                int cx1 = min(GRD - 1, (int)((me.x + RAD - bminx) * inv));
                int cy0 = max(0, (int)((me.y - RAD - bminy) * inv));
                int cy1 = min(GRD - 1, (int)((me.y + RAD - bminy) * inv));
                float bd = 3e38f;
                be = -1;
                int bn = 1 << 30;
                ROW_ARGMIN(cy0, cx0, cx1, me, bd, be, bn);
                if (cy1 > cy0) ROW_ARGMIN(cy1, cx0, cx1, me, bd, be, bn);
                if (be < 0) continue;            // impossible when M > 0
            }
            int r = KRANK(be) - rb;
            if (r >= 0 && r < LDSK) {
                atomicAdd(&ksx[r], me.x);
                atomicAdd(&ksy[r], me.y);
                atomicAdd(&kcn[r], 1.0f);
            }
        }
        __syncthreads();
        for (int e = tid; e < M; e += 1024) {
            unsigned int w = cmb[e];
            if ((w & 3u) != ST_A) continue;
            int r = KRANK(e) - rb;
            if (r < 0 || r >= LDSK) continue;
            int n = (int)(w >> 2);
            float sx = ksx[r], sy = ksy[r], c = kcn[r];
            out[2 * (base + n)]     = sx / c;    // c >= 1 (self-assign)
            out[2 * (base + n) + 1] = sy / c;
            ok[n] = 1.0f;
        }
    }
}

// ---------------------------------------------------------------------------
extern "C" void kernel_launch(void* const* d_in, const int* in_sizes, int n_in,
                              void* d_out, int out_size, void* d_ws, size_t ws_size,
                              hipStream_t stream) {
    const float* seg   = (const float*)d_in[0];   // [B,C,H,W] f32
    const float* lidar = (const float*)d_in[1];   // [B,2,H,W] f32
    float* out = (float*)d_out;

    float* xs = (float*)d_ws;                     // 16384 f
    float* ys = xs + KBLK * KTHR;                 // 16384 f
    unsigned int* ns = (unsigned int*)(ys + KBLK * KTHR);   // 16384 u32
    unsigned int* counts = ns + KBLK * KTHR;      // KBLK*6 u32

    k_front<<<KBLK, KTHR, 0, stream>>>(seg, lidar, xs, ys, ns, counts, out);
    k_nms<<<NP, 1024, 0, stream>>>(xs, ys, ns, counts, out);
}

// Round 10
// 101.575 us; speedup vs baseline: 1.2461x; 1.2461x over previous
//
#include <hip/hip_runtime.h>

#define NPTS 8192      // H*W
#define BCLS 4         // C
#define NP   6         // B*(C-1) pairs
#define R2   9.0f
#define RAD  3.0f
#define GRD  128       // fine grid — cell = max(6, span/127) ~= 2*RAD
#define NCELL (GRD*GRD)
#define PCAP 2048      // pending-list capacity (overflow -> sweep fallback)
#define CAP  4096      // per-pair compact-point capacity (M ~ 2048 +- 40)
#define KBLK 64        // front kernel blocks
#define KTHR 256       // front kernel threads (KBLK*KTHR == B*NPTS)
#define NSL  8         // slices per pair for wide kernels
#define WBLK (NP*NSL)  // 48 wide blocks
#define WTHR 256

#define ST_U 0u
#define ST_A 1u
#define ST_D 2u

// ---------------------------------------------------------------------------
// R23: split R21 (best: 101.7, k_nms 48.1) at the P5 boundary.
// R22 post-mortem: K=4 intra-round rescans +27us — waves run max-over-lanes
// passes and cross-wave chain links never collapse in-round. Calibration from
// that failure: pending-round scans ~9us, fixpoint ~12-15us, round0/P5 scans
// ~2-3us, build ~8-10us => ~15-20us of k_nms still unattributed after five
// theory-first misses. This round buys MEASUREMENT: k_mid (6x1024, R21 verbatim
// through fixpoint+rank, + state dumps) vs k_assign/k_out (R19-proven WIDE
// 48x256 argmin-accumulate / kept-write from L2-resident state). rocprof rows
// then attribute build+NMS vs assignment directly, and P5/P6 get 8x the CUs.
// Monotone-status/tie-break semantics unchanged; no rank windowing needed
// (accumulators sized CAP >= sK).
// ---------------------------------------------------------------------------

__global__ __launch_bounds__(KTHR) void k_front(
    const float* __restrict__ seg, const float* __restrict__ lidar,
    float* __restrict__ xs, float* __restrict__ ys,
    unsigned int* __restrict__ ns, unsigned int* __restrict__ counts,
    float* __restrict__ ksum, float* __restrict__ out)
{
    const int tid = threadIdx.x, lane = tid & 63;
    const int idx = blockIdx.x * KTHR + tid;       // [0, B*NPTS)
    const int b = idx >> 13, n = idx & 8191;

    __shared__ float ex[KTHR], ey[KTHR];
    __shared__ unsigned short en[KTHR];
    __shared__ unsigned int cnt6[6], off6[6], pos6[6];

    if (tid < 6) cnt6[tid] = 0;
    __syncthreads();

    // per-pixel argmax (strict >: first index wins ties)
    const float* segb = seg + (size_t)b * BCLS * NPTS + n;
    float bv = segb[0];
    int bc = 0;
    #pragma unroll
    for (int c = 1; c < BCLS; ++c) {
        float v = segb[(size_t)c * NPTS];
        if (v > bv) { bv = v; bc = c; }
    }
    const float x = lidar[(size_t)b * 2 * NPTS + n];
    const float y = lidar[(size_t)b * 2 * NPTS + NPTS + n];
    const int p = (bc > 0) ? (b * 3 + bc - 1) : -1;

    // phase A: wave-aggregated per-pair counts
    #pragma unroll
    for (int q = 0; q < 6; ++q) {
        unsigned long long bal = __ballot(p == q);
        if (lane == 0 && bal) atomicAdd(&cnt6[q], (unsigned int)__popcll(bal));
    }
    __syncthreads();
    if (tid == 0) {
        unsigned int a = 0;
        #pragma unroll
        for (int q = 0; q < 6; ++q) { off6[q] = a; pos6[q] = a; a += cnt6[q]; }
    }
    __syncthreads();
    // phase B: wave-aggregated placement into pair-grouped staging
    #pragma unroll
    for (int q = 0; q < 6; ++q) {
        unsigned long long bal = __ballot(p == q);
        if (bal) {
            int ldr = __builtin_ctzll(bal);
            unsigned int wb = 0;
            if (lane == ldr) wb = atomicAdd(&pos6[q], (unsigned int)__popcll(bal));
            wb = __shfl(wb, ldr, 64);
            if (p == q) {
                unsigned int s = wb + (unsigned int)__popcll(bal & ((1ull << lane) - 1ull));
                ex[s] = x; ey[s] = y; en[s] = (unsigned short)n;
            }
        }
    }
    __syncthreads();
    // flush grouped staging to this block's slab chunk + counts row
    {
        const unsigned int total = off6[5] + cnt6[5];
        const int gbase = blockIdx.x * KTHR;
        for (int k = tid; k < (int)total; k += KTHR) {
            xs[gbase + k] = ex[k];
            ys[gbase + k] = ey[k];
            ns[gbase + k] = (unsigned int)en[k];
        }
        if (tid < 6) counts[blockIdx.x * 6 + tid] = cnt6[tid];
    }
    // zero out+ok (36864 float4) and ksum = ksx|ksy|kcn (73728 f = 18432 f4)
    {
        float4* o4 = (float4*)out;
        for (int k = idx; k < 36864; k += KBLK * KTHR)
            o4[k] = make_float4(0.f, 0.f, 0.f, 0.f);
        float4* s4 = (float4*)ksum;
        for (int k = idx; k < 18432; k += KBLK * KTHR)
            s4[k] = make_float4(0.f, 0.f, 0.f, 0.f);
    }
}

// ---------------------------------------------------------------------------
__global__ __launch_bounds__(1024) void k_mid(
    const float* __restrict__ xs, const float* __restrict__ ys,
    const unsigned int* __restrict__ ns, const unsigned int* __restrict__ counts,
    float2* __restrict__ sps_g, unsigned int* __restrict__ cmb_g,
    unsigned int* __restrict__ cellpack_g, float* __restrict__ bbox_g,
    int* __restrict__ M_g,
    unsigned long long* __restrict__ ballots_g, unsigned int* __restrict__ base_g)
{
    const int p = blockIdx.x;
    const int tid = threadIdx.x, lane = tid & 63, wv = tid >> 6;

    __shared__ float2 sps[CAP];                 // 32 KB
    __shared__ unsigned int cmb[CAP];           // 16 KB
    __shared__ unsigned int cellpack[NCELL];    // 64 KB
    __shared__ unsigned short plist[2][PCAP];   //  8 KB
    __shared__ int pcnt[2];
    __shared__ unsigned long long ballots[64];
    __shared__ unsigned int base64[64];
    __shared__ unsigned int wtot[16];
    __shared__ float redbuf[4][16];
    __shared__ unsigned int csrc[KBLK], cdst[KBLK];
    __shared__ float sbminx, sbminy, scell;
    __shared__ int sM;

    for (int k = tid; k < CAP; k += 1024) cmb[k] = ST_U;
    for (int k = tid; k < NCELL; k += 1024) cellpack[k] = 0u;
    if (tid == 0) { pcnt[0] = 0; pcnt[1] = 0; }

    // ---- chunk table: lane k of wave 0 owns source block k ----
    if (wv == 0) {
        unsigned int c6[6];
        #pragma unroll
        for (int q = 0; q < 6; ++q) c6[q] = counts[lane * 6 + q];
        unsigned int within = 0;
        for (int q = 0; q < p; ++q) within += c6[q];
        unsigned int len = c6[p];
        unsigned int v = len;
        for (int d = 1; d < 64; d <<= 1) {
            unsigned int u = __shfl_up(v, d, 64);
            if (lane >= d) v += u;
        }
        csrc[lane] = lane * KTHR + within;
        cdst[lane] = v - len;
        if (lane == 63) sM = (int)(v < CAP ? v : CAP);
    }
    __syncthreads();
    const int M = sM;

    // ---- gather compact entries into regs + bbox ----
    float xq[4], yq[4];
    unsigned int nq[4];
    int liq[4];
    {
        float mnx = 3e38f, mxx = -3e38f, mny = 3e38f, mxy = -3e38f;
        #pragma unroll
        for (int q = 0; q < 4; ++q) {
            int li = q * 1024 + tid;
            liq[q] = li;
            if (li < M) {
                int lo = 0, hi = KBLK - 1;          // last k with cdst[k] <= li
                #pragma unroll
                for (int s = 0; s < 6; ++s) {
                    int mid = (lo + hi + 1) >> 1;
                    if (cdst[mid] <= (unsigned int)li) lo = mid; else hi = mid - 1;
                }
                int si = csrc[lo] + (li - cdst[lo]);
                float x = xs[si], y = ys[si];
                xq[q] = x; yq[q] = y; nq[q] = ns[si];
                mnx = fminf(mnx, x); mxx = fmaxf(mxx, x);
                mny = fminf(mny, y); mxy = fmaxf(mxy, y);
            }
        }
        for (int d = 32; d; d >>= 1) {
            mnx = fminf(mnx, __shfl_xor(mnx, d, 64));
            mxx = fmaxf(mxx, __shfl_xor(mxx, d, 64));
            mny = fminf(mny, __shfl_xor(mny, d, 64));
            mxy = fmaxf(mxy, __shfl_xor(mxy, d, 64));
        }
        if (lane == 0) { redbuf[0][wv] = mnx; redbuf[1][wv] = mxx;
                         redbuf[2][wv] = mny; redbuf[3][wv] = mxy; }
    }
    __syncthreads();
    if (tid == 0) {
        float a = redbuf[0][0], b2 = redbuf[1][0], c = redbuf[2][0], d = redbuf[3][0];
        for (int q = 1; q < 16; ++q) {
            a = fminf(a, redbuf[0][q]); b2 = fmaxf(b2, redbuf[1][q]);
            c = fminf(c, redbuf[2][q]); d = fmaxf(d, redbuf[3][q]);
        }
        sbminx = a; sbminy = c;
        scell = fmaxf(2.0f * RAD, fmaxf(b2 - a, d - c) / 127.0f);  // cell >= 2*RAD
    }
    __syncthreads();
    const float bminx = sbminx, bminy = sbminy, inv = 1.0f / scell;

    // ---- grid count / scan / scatter (coords held in regs) ----
    int cellq[4];
    #pragma unroll
    for (int q = 0; q < 4; ++q) {
        if (liq[q] < M) {
            int ix = min(GRD - 1, max(0, (int)((xq[q] - bminx) * inv)));
            int iy = min(GRD - 1, max(0, (int)((yq[q] - bminy) * inv)));
            cellq[q] = iy * GRD + ix;
            atomicAdd(&cellpack[cellq[q]], 1u);
        } else cellq[q] = -1;
    }
    __syncthreads();
    {
        unsigned int c16[16], t16 = 0;          // thread owns 16 cells
        #pragma unroll
        for (int q = 0; q < 16; ++q) { c16[q] = cellpack[tid * 16 + q]; t16 += c16[q]; }
        unsigned int v = t16;
        for (int d = 1; d < 64; d <<= 1) {
            unsigned int u = __shfl_up(v, d, 64);
            if (lane >= d) v += u;
        }
        if (lane == 63) wtot[wv] = v;
        __syncthreads();
        if (tid == 0) {
            unsigned int acc = 0;
            for (int q = 0; q < 16; ++q) { unsigned int t = wtot[q]; wtot[q] = acc; acc += t; }
        }
        __syncthreads();
        unsigned int excl = wtot[wv] + v - t16;
        #pragma unroll
        for (int q = 0; q < 16; ++q) { cellpack[tid * 16 + q] = excl << 16; excl += c16[q]; }
    }
    __syncthreads();
    #pragma unroll
    for (int q = 0; q < 4; ++q) {
        if (cellq[q] >= 0) {
            unsigned int old = atomicAdd(&cellpack[cellq[q]], 1u);
            unsigned int pos = (old >> 16) + (old & 0xffffu);
            sps[pos] = make_float2(xq[q], yq[q]);
            cmb[pos] = (nq[q] << 2) | ST_U;
        }
    }   // cellpack now = start<<16 | cnt; sps/cmb grid-space
    __syncthreads();

    // ---- dump build state (sps/cellpack/bbox/M don't change after here) ----
    const int pb = p * CAP;
    for (int k = tid; k < CAP; k += 1024) sps_g[pb + k] = sps[k];
    for (int k = tid; k < NCELL; k += 1024) cellpack_g[p * NCELL + k] = cellpack[k];
    if (tid == 0) {
        bbox_g[p * 4 + 0] = bminx; bbox_g[p * 4 + 1] = bminy;
        bbox_g[p * 4 + 2] = inv;
        M_g[p] = M;
    }

    // flat window row scan over two contiguous streams (branchless)
    #define ROW_FLAGS(CY, CX0, CX1, NI, ME, DEAD, UNDEC)                          \
    {                                                                             \
        unsigned int wa = cellpack[(CY) * GRD + (CX0)];                           \
        unsigned int wb = cellpack[(CY) * GRD + (CX1)];                           \
        unsigned int f0 = wa >> 16, f1 = (wb >> 16) + (wb & 0xffffu);             \
        for (unsigned int f = f0; f < f1; ++f) {                                  \
            unsigned int wf = cmb[f];                                             \
            float2 q = sps[f];                                                    \
            float dx = __fsub_rn((ME).x, q.x), dy = __fsub_rn((ME).y, q.y);       \
            float d2 = __fadd_rn(__fmul_rn(dx, dx), __fmul_rn(dy, dy));           \
            bool in = (d2 < R2) & ((int)(wf >> 2) < (NI));                        \
            DEAD  |= in & ((wf & 3u) == ST_A);                                    \
            UNDEC |= in & ((wf & 3u) == ST_U);                                    \
        }                                                                         \
    }
    #define SCAN_FLAGS(NI, ME, DEAD, UNDEC)                                       \
    {                                                                             \
        int cx0 = max(0, (int)(((ME).x - RAD - bminx) * inv));                    \
        int cx1 = min(GRD - 1, (int)(((ME).x + RAD - bminx) * inv));              \
        int cy0 = max(0, (int)(((ME).y - RAD - bminy) * inv));                    \
        int cy1 = min(GRD - 1, (int)(((ME).y + RAD - bminy) * inv));              \
        DEAD = false; UNDEC = false;                                              \
        ROW_FLAGS(cy0, cx0, cx1, NI, ME, DEAD, UNDEC);                            \
        if (cy1 > cy0) ROW_FLAGS(cy1, cx0, cx1, NI, ME, DEAD, UNDEC);             \
    }

    // ---- P4 round 0: full sweep (grid order), wave-ordered pending append ----
    for (int e = tid; e < M; e += 1024) {
        unsigned int w = cmb[e];
        int ni = (int)(w >> 2);
        float2 me = sps[e];
        bool dead, undec;
        SCAN_FLAGS(ni, me, dead, undec);
        if (dead) cmb[e] = (w & ~3u) | ST_D;
        else if (!undec) cmb[e] = (w & ~3u) | ST_A;
        bool pendf = !dead && undec;
        unsigned long long act = __ballot(true);
        unsigned long long bal = __ballot(pendf);
        int leader = __builtin_ctzll(act);
        int cnt = __popcll(bal);
        int wbase = 0;
        if (lane == leader && cnt) wbase = atomicAdd(&pcnt[0], cnt);
        wbase = __shfl(wbase, leader, 64);
        if (pendf) {
            int pos = wbase + __popcll(bal & ((1ull << lane) - 1ull));
            if (pos < PCAP) plist[0][pos] = (unsigned short)e;
        }
    }

    // ---- P4 rounds over compacted pending (proven R11 engine) ----
    int cur = 0;
    for (int round = 0; round < NPTS; ++round) {
        __syncthreads();
        int pc = pcnt[cur];
        if (pc == 0) break;
        if (pc > PCAP) {                        // overflow fallback: full sweeps
            for (;;) {
                bool any = false;
                __syncthreads();
                for (int e = tid; e < M; e += 1024) {
                    unsigned int w = cmb[e];
                    if ((w & 3u) != ST_U) continue;
                    int ni = (int)(w >> 2);
                    float2 me = sps[e];
                    bool dead, undec;
                    SCAN_FLAGS(ni, me, dead, undec);
                    if (dead) cmb[e] = (w & ~3u) | ST_D;
                    else if (!undec) cmb[e] = (w & ~3u) | ST_A;
                    else any = true;
                }
                if (__syncthreads_count(any) == 0) break;
            }
            break;
        }
        if (tid == 0) pcnt[cur ^ 1] = 0;
        __syncthreads();
        for (int idx = tid; idx < pc; idx += 1024) {
            int e = plist[cur][idx];
            unsigned int w = cmb[e];
            int ni = (int)(w >> 2);
            float2 me = sps[e];
            bool dead, undec;
            SCAN_FLAGS(ni, me, dead, undec);
            if (dead) cmb[e] = (w & ~3u) | ST_D;
            else if (!undec) cmb[e] = (w & ~3u) | ST_A;
            bool pendf = !dead && undec;
            unsigned long long act = __ballot(true);
            unsigned long long bal = __ballot(pendf);
            int leader = __builtin_ctzll(act);
            int cnt = __popcll(bal);
            int wbase = 0;
            if (lane == leader && cnt) wbase = atomicAdd(&pcnt[cur ^ 1], cnt);
            wbase = __shfl(wbase, leader, 64);
            if (pendf) {
                int pos = wbase + __popcll(bal & ((1ull << lane) - 1ull));
                if (pos < PCAP) plist[cur ^ 1][pos] = (unsigned short)e;
            }
        }
        cur ^= 1;
    }
    __syncthreads();

    // ---- kept-rank: ballot bitmask + wave-scanned prefix; dump cmb + rank ----
    for (int k = 0; k < 4; ++k) {
        int e = (k << 10) + tid;
        unsigned long long bal = __ballot((cmb[e] & 3u) == ST_A);  // e>=M stays U
        if (lane == 0) ballots[(k << 4) + wv] = bal;
    }
    __syncthreads();
    if (wv == 0) {
        unsigned int s = (unsigned int)__popcll(ballots[lane]);
        unsigned int v = s;
        for (int d = 1; d < 64; d <<= 1) {
            unsigned int u = __shfl_up(v, d, 64);
            if (lane >= d) v += u;
        }
        base64[lane] = v - s;
    }
    __syncthreads();
    for (int k = tid; k < CAP; k += 1024) cmb_g[pb + k] = cmb[k];
    if (tid < 64) { ballots_g[(p << 6) + tid] = ballots[tid]; base_g[(p << 6) + tid] = base64[tid]; }
}

#define KRANK_G(P, E) ((int)base_g[((P) << 6) + ((E) >> 6)] +                     \
    __popcll(ballots_g[((P) << 6) + ((E) >> 6)] & ((1ull << ((E) & 63)) - 1ull)))

// ---------------------------------------------------------------------------
__global__ __launch_bounds__(WTHR) void k_assign(
    const float2* __restrict__ sps_g, const unsigned int* __restrict__ cmb_g,
    const unsigned int* __restrict__ cellpack_g, const float* __restrict__ bbox_g,
    const int* __restrict__ M_g,
    const unsigned long long* __restrict__ ballots_g, const unsigned int* __restrict__ base_g,
    float* __restrict__ ksx, float* __restrict__ ksy, float* __restrict__ kcn)
{
    const int p = blockIdx.x / NSL, s = blockIdx.x % NSL;
    const int tid = threadIdx.x;
    const int M = M_g[p];
    const float bminx = bbox_g[p * 4], bminy = bbox_g[p * 4 + 1], inv = bbox_g[p * 4 + 2];
    const float2* sp = sps_g + p * CAP;
    const unsigned int* cm = cmb_g + p * CAP;
    const unsigned int* cp = cellpack_g + p * NCELL;

    const int chunk = (M + NSL - 1) / NSL;
    const int e0 = s * chunk, e1 = min(M, e0 + chunk);

    #define G_ROW_ARGMIN(CY, CX0, CX1, ME, BD, BE, BN)                            \
    {                                                                             \
        unsigned int wa = cp[(CY) * GRD + (CX0)];                                 \
        unsigned int wb = cp[(CY) * GRD + (CX1)];                                 \
        unsigned int f0 = wa >> 16, f1 = (wb >> 16) + (wb & 0xffffu);             \
        for (unsigned int f = f0; f < f1; ++f) {                                  \
            unsigned int wf = cm[f];                                              \
            float2 q = sp[f];                                                     \
            float dx = __fsub_rn((ME).x, q.x), dy = __fsub_rn((ME).y, q.y);       \
            float d2 = __fadd_rn(__fmul_rn(dx, dx), __fmul_rn(dy, dy));           \
            int nf = (int)(wf >> 2);                                              \
            bool better = ((wf & 3u) == ST_A) &                                   \
                          ((d2 < BD) | ((d2 == BD) & (nf < BN)));                 \
            BD = better ? d2 : BD;                                                \
            BE = better ? (int)f : BE;                                            \
            BN = better ? nf : BN;                                                \
        }                                                                         \
    }
    for (int e = e0 + tid; e < e1; e += WTHR) {
        unsigned int w = cm[e];
        float2 me = sp[e];
        int be;
        if ((w & 3u) == ST_A) {
            be = e;                              // self: unique d2 = 0
        } else {
            int cx0 = max(0, (int)((me.x - RAD - bminx) * inv));
            int cx1 = min(GRD - 1, (int)((me.x + RAD - bminx) * inv));
            int cy0 = max(0, (int)((me.y - RAD - bminy) * inv));
            int cy1 = min(GRD - 1, (int)((me.y + RAD - bminy) * inv));
            float bd = 3e38f;
            be = -1;
            int bn = 1 << 30;
            G_ROW_ARGMIN(cy0, cx0, cx1, me, bd, be, bn);
            if (cy1 > cy0) G_ROW_ARGMIN(cy1, cx0, cx1, me, bd, be, bn);
            if (be < 0) continue;
        }
        int r = KRANK_G(p, be);
        atomicAdd(&ksx[p * CAP + r], me.x);
        atomicAdd(&ksy[p * CAP + r], me.y);
        atomicAdd(&kcn[p * CAP + r], 1.0f);
    }
}

// ---------------------------------------------------------------------------
__global__ __launch_bounds__(WTHR) void k_out(
    const unsigned int* __restrict__ cmb_g, const int* __restrict__ M_g,
    const unsigned long long* __restrict__ ballots_g, const unsigned int* __restrict__ base_g,
    const float* __restrict__ ksx, const float* __restrict__ ksy,
    const float* __restrict__ kcn, float* __restrict__ out)
{
    const int p = blockIdx.x / NSL, s = blockIdx.x % NSL;
    const int tid = threadIdx.x;
    const int M = M_g[p];
    const unsigned int* cm = cmb_g + p * CAP;
    const int base = p * NPTS;
    float* ok = out + (size_t)2 * NP * NPTS + base;

    const int chunk = (M + NSL - 1) / NSL;
    const int e0 = s * chunk, e1 = min(M, e0 + chunk);

    for (int e = e0 + tid; e < e1; e += WTHR) {
        unsigned int w = cm[e];
        if ((w & 3u) != ST_A) continue;
        int n = (int)(w >> 2);
        int r = KRANK_G(p, e);
        float c = kcn[p * CAP + r];
        out[2 * (base + n)]     = ksx[p * CAP + r] / c;   // c >= 1 (self-assign)
        out[2 * (base + n) + 1] = ksy[p * CAP + r] / c;
        ok[n] = 1.0f;
    }
}

// ---------------------------------------------------------------------------
extern "C" void kernel_launch(void* const* d_in, const int* in_sizes, int n_in,
                              void* d_out, int out_size, void* d_ws, size_t ws_size,
                              hipStream_t stream) {
    const float* seg   = (const float*)d_in[0];   // [B,C,H,W] f32
    const float* lidar = (const float*)d_in[1];   // [B,2,H,W] f32
    float* out = (float*)d_out;
    float* wsf = (float*)d_ws;

    float* xs = wsf;                                          // 16384
    float* ys = wsf + 16384;                                  // 16384
    unsigned int* ns = (unsigned int*)(wsf + 32768);          // 16384
    unsigned int* counts = (unsigned int*)(wsf + 49152);      // 384
    float2* sps_g = (float2*)(wsf + 49536);                   // 6*4096 f2 -> 98688
    unsigned int* cmb_g = (unsigned int*)(wsf + 98688);       // 24576    -> 123264
    unsigned int* cellpack_g = (unsigned int*)(wsf + 123264); // 98304    -> 221568
    float* bbox_g = wsf + 221568;                             // 24
    int* M_g = (int*)(wsf + 221592);                          // 6 (+2 pad)
    unsigned long long* ballots_g = (unsigned long long*)(wsf + 221600); // 384 u64
    unsigned int* base_g = (unsigned int*)(wsf + 222368);     // 384
    float* ksx = wsf + 222752;                                // 24576
    float* ksy = wsf + 247328;                                // 24576
    float* kcn = wsf + 271904;                                // 24576

    k_front <<<KBLK, KTHR, 0, stream>>>(seg, lidar, xs, ys, ns, counts, ksx, out);
    k_mid   <<<NP, 1024, 0, stream>>>(xs, ys, ns, counts, sps_g, cmb_g, cellpack_g,
                                      bbox_g, M_g, ballots_g, base_g);
    k_assign<<<WBLK, WTHR, 0, stream>>>(sps_g, cmb_g, cellpack_g, bbox_g, M_g,
                                        ballots_g, base_g, ksx, ksy, kcn);
    k_out   <<<WBLK, WTHR, 0, stream>>>(cmb_g, M_g, ballots_g, base_g, ksx, ksy, kcn, out);
}